// Round 13
// baseline (691.914 us; speedup 1.0000x reference)
//
#include <hip/hip_runtime.h>
#include <hip/hip_bf16.h>
#include <math.h>

// Problem: B=16, N=512, D=256, H=8, L=4, DFF=1024, K=128, DH=32
#define BB 16
#define NN 512
#define DD 256
#define HH 8
#define LL 4
#define DFF 1024
#define KSEL 128
#define DH 32

typedef __attribute__((ext_vector_type(8))) short bf16x8v;
typedef __attribute__((ext_vector_type(4))) float f32x4v;

// ---------------- workspace layout (byte offsets) ----------------
static const size_t X_B    = 0;
static const size_t QKVB_B = 8388608;
static const size_t VT_B   = 20971520;
static const size_t FFN_B  = 8388608;    // overlays qkvb+Vt (dead during FFN)
static const size_t H_B    = 25165824;
static const size_t ATT_B  = 29360128;
static const size_t WQKV_B = 33554432;
static const size_t WO_B   = 35127296;
static const size_t W1T_B  = 35651584;
static const size_t W2T_B  = 37748736;
static const size_t S_B    = 39845888;
static const size_t MAXD_B = 39878656;   // S_B + 32768
static const size_t IDX_B  = 39878720;   // MAXD_B + 64
static const size_t DUMMY_B = 39886912;  // IDX_B + 8192

// ---------------- helpers ----------------
__device__ __forceinline__ float gelu_f(float x) {
  float x3 = x * x * x;
  return 0.5f * x * (1.f + tanhf(0.7978845608028654f * (x + 0.044715f * x3)));
}

__device__ __forceinline__ short bf16raw(float v) {
  __hip_bfloat16 h = __float2bfloat16(v);
  return *reinterpret_cast<short*>(&h);
}

__device__ __forceinline__ float blk_sum_256(float v, float* stmp) {
  #pragma unroll
  for (int o = 32; o > 0; o >>= 1) v += __shfl_down(v, o, 64);
  if ((threadIdx.x & 63) == 0) stmp[threadIdx.x >> 6] = v;
  __syncthreads();
  if (threadIdx.x == 0) stmp[0] = stmp[0] + stmp[1] + stmp[2] + stmp[3];
  __syncthreads();
  float r = stmp[0];
  __syncthreads();
  return r;
}

// DPP move of a u64, invalid lanes -> 0 (bound_ctrl=1). CTRL is a DPP code.
template <int CTRL>
__device__ __forceinline__ unsigned long long dpp_mov_u64(unsigned long long x) {
  int lo = __builtin_amdgcn_update_dpp(0, (int)(unsigned)x, CTRL, 0xf, 0xf, true);
  int hi = __builtin_amdgcn_update_dpp(0, (int)(unsigned)(x >> 32), CTRL, 0xf, 0xf, true);
  return ((unsigned long long)(unsigned)hi << 32) | (unsigned)lo;
}

// merge sorted pairs (b1>=b2), (n1>=n2) -> top-2 into (b1,b2)
__device__ __forceinline__ void merge_top2(unsigned long long& b1, unsigned long long& b2,
                                           unsigned long long n1, unsigned long long n2) {
  if (n1 > b1) {
    b2 = (b1 > n2) ? b1 : n2;
    b1 = n1;
  } else {
    b2 = (b2 > n1) ? b2 : n1;
  }
}

// ---------------- kernels ----------------

// one-shot: transpose-cast all weights to bf16.
__global__ __launch_bounds__(256) void cast_weights_kernel(
    const float* __restrict__ Wq, const float* __restrict__ Wk,
    const float* __restrict__ Wv, const float* __restrict__ Wo,
    const float* __restrict__ W1, const float* __restrict__ W2,
    __hip_bfloat16* __restrict__ qkvT, __hip_bfloat16* __restrict__ WoT,
    __hip_bfloat16* __restrict__ W1T, __hip_bfloat16* __restrict__ W2T) {
  int i = blockIdx.x * 256 + threadIdx.x;
  if (i < 786432) {                       // qkvT [L][768 n][256 k]
    int l = i / 196608, r = i % 196608;
    int n = r >> 8, k = r & 255;
    const float* src = (n < 256) ? Wq : (n < 512 ? Wk : Wv);
    qkvT[i] = __float2bfloat16(src[l * 65536 + k * 256 + (n & 255)]);
  } else if (i < 1048576) {               // WoT [L][256][256]
    int j = i - 786432;
    int l = j >> 16, r = j & 65535;
    int n = r >> 8, k = r & 255;
    WoT[j] = __float2bfloat16(Wo[l * 65536 + k * 256 + n]);
  } else if (i < 2097152) {               // W1T [L][1024 n][256 k]
    int j = i - 1048576;
    int l = j >> 18, r = j & 262143;
    int n = r >> 8, k = r & 255;
    W1T[j] = __float2bfloat16(W1[l * 262144 + k * 1024 + n]);
  } else {                                // W2T [L][256 n][1024 k]
    int j = i - 2097152;
    int l = j >> 18, r = j & 262143;
    int n = r >> 10, k = r & 1023;
    W2T[j] = __float2bfloat16(W2[l * 262144 + k * 256 + n]);
  }
}

// LayerNorm, writes bf16. One wave per row, shfl reductions, no LDS.
__global__ __launch_bounds__(256) void ln_cast_kernel(const float* __restrict__ in,
                                                      const float* __restrict__ g,
                                                      const float* __restrict__ bb,
                                                      __hip_bfloat16* __restrict__ out) {
  const int tid = threadIdx.x;
  const int lane = tid & 63;
  const size_t row = (size_t)blockIdx.x * 4 + (tid >> 6);
  const float4 v = *(const float4*)(in + row * DD + lane * 4);
  float s1 = v.x + v.y + v.z + v.w;
  #pragma unroll
  for (int o = 32; o > 0; o >>= 1) s1 += __shfl_xor(s1, o, 64);
  const float mu = s1 * (1.f / DD);
  const float d0 = v.x - mu, d1 = v.y - mu, d2 = v.z - mu, d3 = v.w - mu;
  float s2 = d0 * d0 + d1 * d1 + d2 * d2 + d3 * d3;
  #pragma unroll
  for (int o = 32; o > 0; o >>= 1) s2 += __shfl_xor(s2, o, 64);
  const float rsig = rsqrtf(s2 * (1.f / DD) + 1e-6f);
  const float4 gg = *(const float4*)(g + lane * 4);
  const float4 bv = *(const float4*)(bb + lane * 4);
  short4 o;
  o.x = bf16raw(d0 * rsig * gg.x + bv.x);
  o.y = bf16raw(d1 * rsig * gg.y + bv.y);
  o.z = bf16raw(d2 * rsig * gg.z + bv.z);
  o.w = bf16raw(d3 * rsig * gg.w + bv.w);
  *(short4*)((short*)out + row * DD + lane * 4) = o;
}

// MFMA bf16 GEMM (64x64 tile, BK=64, 4 waves). LDS pitch 72 shorts.
// MODE 2: bf16 out = gelu(acc);
// MODE 3: qkv: cols<512 -> bf16 qkvb (pitch 768); cols>=512 -> Vt[b][dim][key].
template <int MODE>
__global__ __launch_bounds__(256) void mfma_gemm(const __hip_bfloat16* __restrict__ A,
                                                 const __hip_bfloat16* __restrict__ Bt,
                                                 void* __restrict__ Cv,
                                                 __hip_bfloat16* __restrict__ Vto,
                                                 int M, int N, int Kd) {
  __shared__ short As[64 * 72];
  __shared__ short Bs[64 * 72];
  const int tid = threadIdx.x;
  const int w = tid >> 6, lane = tid & 63;
  const int m16 = lane & 15, quad = lane >> 4;
  const int bm = blockIdx.y << 6, bn = blockIdx.x << 6;
  const int srow = tid >> 2, scol = (tid & 3) << 3;

  f32x4v acc[4];
  #pragma unroll
  for (int nt = 0; nt < 4; ++nt) acc[nt] = (f32x4v){0.f, 0.f, 0.f, 0.f};

  const short* Ag = (const short*)A;
  const short* Bg = (const short*)Bt;

  for (int k0 = 0; k0 < Kd; k0 += 64) {
    const short* Agr = Ag + (size_t)(bm + srow) * Kd + k0 + scol;
    const short* Bgr = Bg + (size_t)(bn + srow) * Kd + k0 + scol;
    *(bf16x8v*)&As[srow * 72 + scol]      = *(const bf16x8v*)Agr;
    *(bf16x8v*)&As[srow * 72 + 32 + scol] = *(const bf16x8v*)(Agr + 32);
    *(bf16x8v*)&Bs[srow * 72 + scol]      = *(const bf16x8v*)Bgr;
    *(bf16x8v*)&Bs[srow * 72 + 32 + scol] = *(const bf16x8v*)(Bgr + 32);
    __syncthreads();
    #pragma unroll
    for (int kt = 0; kt < 2; ++kt) {
      bf16x8v af = *(bf16x8v*)&As[(w * 16 + m16) * 72 + (kt << 5) + (quad << 3)];
      #pragma unroll
      for (int nt = 0; nt < 4; ++nt) {
        bf16x8v bf = *(bf16x8v*)&Bs[(nt * 16 + m16) * 72 + (kt << 5) + (quad << 3)];
        acc[nt] = __builtin_amdgcn_mfma_f32_16x16x32_bf16(af, bf, acc[nt], 0, 0, 0);
      }
    }
    __syncthreads();
  }

  const int erow = bm + w * 16 + quad * 4;
  #pragma unroll
  for (int nt = 0; nt < 4; ++nt) {
    int col = bn + nt * 16 + m16;
    if (MODE == 3) {
      if (col < 512) {
        #pragma unroll
        for (int r = 0; r < 4; ++r)
          ((__hip_bfloat16*)Cv)[(size_t)(erow + r) * 768 + col] =
              __float2bfloat16(acc[nt][r]);
      } else {
        short4 pk;
        pk.x = bf16raw(acc[nt][0]); pk.y = bf16raw(acc[nt][1]);
        pk.z = bf16raw(acc[nt][2]); pk.w = bf16raw(acc[nt][3]);
        int bb2 = erow >> 9, key = erow & 511, dim = col - 512;
        *(short4*)((short*)Vto + (size_t)bb2 * 131072 + (size_t)dim * 512 + key) = pk;
      }
    } else {
      #pragma unroll
      for (int r = 0; r < 4; ++r)
        ((__hip_bfloat16*)Cv)[(size_t)(erow + r) * N + col] =
            __float2bfloat16(gelu_f(acc[nt][r]));
    }
  }
}

// gemm body (BK=64): fp32 out = acc + Res (Wo / FFN2). bm passed in.
__device__ __forceinline__ void gemm_res_body(const __hip_bfloat16* __restrict__ A,
                                              const __hip_bfloat16* __restrict__ Bt,
                                              const float* __restrict__ Res,
                                              float* __restrict__ C,
                                              int N, int Kd, int bm,
                                              short* As, short* Bs) {
  const int tid = threadIdx.x;
  const int w = tid >> 6, lane = tid & 63;
  const int m16 = lane & 15, quad = lane >> 4;
  const int bn = blockIdx.x << 6;
  const int srow = tid >> 2, scol = (tid & 3) << 3;

  f32x4v acc[4];
  #pragma unroll
  for (int nt = 0; nt < 4; ++nt) acc[nt] = (f32x4v){0.f, 0.f, 0.f, 0.f};

  const short* Ag = (const short*)A;
  const short* Bg = (const short*)Bt;

  for (int k0 = 0; k0 < Kd; k0 += 64) {
    const short* Agr = Ag + (size_t)(bm + srow) * Kd + k0 + scol;
    const short* Bgr = Bg + (size_t)(bn + srow) * Kd + k0 + scol;
    *(bf16x8v*)&As[srow * 72 + scol]      = *(const bf16x8v*)Agr;
    *(bf16x8v*)&As[srow * 72 + 32 + scol] = *(const bf16x8v*)(Agr + 32);
    *(bf16x8v*)&Bs[srow * 72 + scol]      = *(const bf16x8v*)Bgr;
    *(bf16x8v*)&Bs[srow * 72 + 32 + scol] = *(const bf16x8v*)(Bgr + 32);
    __syncthreads();
    #pragma unroll
    for (int kt = 0; kt < 2; ++kt) {
      bf16x8v af = *(bf16x8v*)&As[(w * 16 + m16) * 72 + (kt << 5) + (quad << 3)];
      #pragma unroll
      for (int nt = 0; nt < 4; ++nt) {
        bf16x8v bf = *(bf16x8v*)&Bs[(nt * 16 + m16) * 72 + (kt << 5) + (quad << 3)];
        acc[nt] = __builtin_amdgcn_mfma_f32_16x16x32_bf16(af, bf, acc[nt], 0, 0, 0);
      }
    }
    __syncthreads();
  }

  const int erow = bm + w * 16 + quad * 4;
  #pragma unroll
  for (int nt = 0; nt < 4; ++nt) {
    int col = bn + nt * 16 + m16;
    #pragma unroll
    for (int r = 0; r < 4; ++r) {
      size_t off = (size_t)(erow + r) * N + col;
      C[off] = acc[nt][r] + Res[off];
    }
  }
}

__global__ __launch_bounds__(256) void mfma_gemm_res(const __hip_bfloat16* __restrict__ A,
                                                     const __hip_bfloat16* __restrict__ Bt,
                                                     const float* __restrict__ Res,
                                                     float* __restrict__ C,
                                                     int N, int Kd) {
  __shared__ short As[64 * 72];
  __shared__ short Bs[64 * 72];
  gemm_res_body(A, Bt, Res, C, N, Kd, blockIdx.y << 6, As, Bs);
}

// AFPS selection for ONE batch, one wave. DPP top-2 argmax + 1-deep spec.
__device__ void afps_wave(int b, int lane,
                          const float* __restrict__ dist,
                          const float* __restrict__ s,
                          const unsigned int* __restrict__ maxd,
                          int* __restrict__ idx_out) {
  const float* db = dist + (size_t)b * NN * NN;

  float sv[8];
  float ms = 0.f;
  #pragma unroll
  for (int r = 0; r < 8; ++r) {
    sv[r] = s[b * NN + r * 64 + lane];
    ms = fmaxf(ms, sv[r]);
  }
  #pragma unroll
  for (int o = 32; o > 0; o >>= 1) ms = fmaxf(ms, __shfl_xor(ms, o, 64));

  const float invmaxd = 1.0f / __uint_as_float(maxd[b]);
  float sn[8], mind[8];
  #pragma unroll
  for (int r = 0; r < 8; ++r) {
    sn[r] = (sv[r] / ms) * 0.1f;
    mind[r] = db[r * 64 + lane] * invmaxd + sn[r];   // row 0 == col 0 (sym)
  }
  unsigned selm = (lane == 0) ? 1u : 0u;
  if (lane == 0) idx_out[b * KSEL + 0] = 0;

  int specIdx = -1;
  float sreg[8];

  for (int it = 1; it < KSEL; ++it) {
    unsigned long long b1 = 0ull, b2 = 0ull;
    #pragma unroll
    for (int r = 0; r < 8; ++r) {
      unsigned long long pk =
          ((selm >> r) & 1u) ? 0ull
            : (((unsigned long long)__float_as_uint(mind[r])) << 32) |
              (unsigned)(511 - (r * 64 + lane));
      if (pk > b1) { b2 = b1; b1 = pk; }
      else if (pk > b2) b2 = pk;
    }
    { unsigned long long n1 = dpp_mov_u64<0x111>(b1), n2 = dpp_mov_u64<0x111>(b2); merge_top2(b1, b2, n1, n2); }
    { unsigned long long n1 = dpp_mov_u64<0x112>(b1), n2 = dpp_mov_u64<0x112>(b2); merge_top2(b1, b2, n1, n2); }
    { unsigned long long n1 = dpp_mov_u64<0x114>(b1), n2 = dpp_mov_u64<0x114>(b2); merge_top2(b1, b2, n1, n2); }
    { unsigned long long n1 = dpp_mov_u64<0x118>(b1), n2 = dpp_mov_u64<0x118>(b2); merge_top2(b1, b2, n1, n2); }
    { unsigned long long n1 = dpp_mov_u64<0x142>(b1), n2 = dpp_mov_u64<0x142>(b2); merge_top2(b1, b2, n1, n2); }
    { unsigned long long n1 = dpp_mov_u64<0x143>(b1), n2 = dpp_mov_u64<0x143>(b2); merge_top2(b1, b2, n1, n2); }
    const unsigned w1 = (unsigned)__builtin_amdgcn_readlane((int)(unsigned)b1, 63);
    const unsigned w2 = (unsigned)__builtin_amdgcn_readlane((int)(unsigned)b2, 63);
    const int nw = 511 - (int)(w1 & 0x1ffu);
    const int sec = 511 - (int)(w2 & 0x1ffu);

    float rowv[8];
    if (nw == specIdx) {
      #pragma unroll
      for (int r = 0; r < 8; ++r) rowv[r] = sreg[r];
    } else {
      const float* row = db + (size_t)nw * NN;
      #pragma unroll
      for (int r = 0; r < 8; ++r) rowv[r] = row[r * 64 + lane];
    }
    {
      const float* srow = db + (size_t)sec * NN;
      #pragma unroll
      for (int r = 0; r < 8; ++r) sreg[r] = srow[r * 64 + lane];
      specIdx = sec;
    }
    if (lane == (nw & 63)) selm |= 1u << (nw >> 6);
    if (lane == 0) idx_out[b * KSEL + it] = nw;
    #pragma unroll
    for (int r = 0; r < 8; ++r)
      mind[r] = fminf(mind[r], fmaf(rowv[r], invmaxd, sn[r]));
  }
}

// Layer-3 Wo GEMM with AFPS fused in grid-y slices 0..3 (dispatched first):
// 16 blocks, one per batch: wave 0 = selector; waves 1-3 warm dist[b] into
// this CU's XCD L2 (selector misses then hit local L2, not HBM/L3).
// gemm blocks use y-4 as row tile.
__global__ __launch_bounds__(256) void wo_gemm_afps(const __hip_bfloat16* __restrict__ A,
                                                    const __hip_bfloat16* __restrict__ Bt,
                                                    const float* __restrict__ Res,
                                                    float* __restrict__ C,
                                                    const float* __restrict__ dist,
                                                    const float* __restrict__ s,
                                                    const unsigned int* __restrict__ maxd,
                                                    int* __restrict__ idx_out,
                                                    float* __restrict__ dummy) {
  __shared__ short As[64 * 72];
  __shared__ short Bs[64 * 72];
  if (blockIdx.y < 4) {
    const int b = blockIdx.y * 4 + blockIdx.x;   // grid.x == 4
    const int wv = threadIdx.x >> 6, lane = threadIdx.x & 63;
    if (wv == 0) {
      afps_wave(b, lane, dist, s, maxd, idx_out);
    } else {
      const float4* p = (const float4*)(dist + (size_t)b * NN * NN);
      float acc = 0.f;
      for (int i = (wv - 1) * 64 + lane; i < 65536; i += 192) acc += p[i].x;
      if (acc == 123.456789f) atomicAdd(dummy, 1.f);  // never true; keeps loads
    }
    return;
  }
  gemm_res_body(A, Bt, Res, C, DD, 256, (blockIdx.y - 4) << 6, As, Bs);
}

// MFMA flash attention, barrier-free.
__global__ __launch_bounds__(512) void attn_kernel(const __hip_bfloat16* __restrict__ qkvb,
                                                   const __hip_bfloat16* __restrict__ vt,
                                                   const float* __restrict__ dist,
                                                   __hip_bfloat16* __restrict__ outg,
                                                   float* __restrict__ s_acc,
                                                   int accum) {
  __shared__ float Pf[8][16 * 36];
  const int tid = threadIdx.x;
  const int h = tid >> 6, lane = tid & 63;
  const int m16 = lane & 15, quad = lane >> 4;
  const int b = blockIdx.y;
  const int qbase = blockIdx.x * 16;
  const float scale = 0.17677669529663687f;
  const f32x4v zero = {0.f, 0.f, 0.f, 0.f};

  const short* qkvs = (const short*)qkvb;
  const short* vts = (const short*)vt + (size_t)b * 131072;
  float* Pw = Pf[h];

  bf16x8v qf = *(const bf16x8v*)(qkvs + ((size_t)(b * NN + qbase + m16)) * 768 + h * 32 + (quad << 3));

  int drow[4];
  #pragma unroll
  for (int r = 0; r < 4; ++r) drow[r] = (b * NN + qbase + quad * 4 + r) * NN;

  f32x4v accO0 = zero, accO1 = zero;
  float laccL[4] = {0.f, 0.f, 0.f, 0.f};

  for (int t0 = 0; t0 < NN; t0 += 32) {
    bf16x8v kf0 = *(const bf16x8v*)(qkvs + ((size_t)(b * NN + t0 + m16)) * 768 + 256 + h * 32 + (quad << 3));
    bf16x8v kf1 = *(const bf16x8v*)(qkvs + ((size_t)(b * NN + t0 + 16 + m16)) * 768 + 256 + h * 32 + (quad << 3));
    f32x4v s0 = __builtin_amdgcn_mfma_f32_16x16x32_bf16(qf, kf0, zero, 0, 0, 0);
    f32x4v s1 = __builtin_amdgcn_mfma_f32_16x16x32_bf16(qf, kf1, zero, 0, 0, 0);
    #pragma unroll
    for (int r = 0; r < 4; ++r) {
      float e0 = __expf(fmaf(s0[r], scale, -dist[drow[r] + t0 + m16]));
      float e1 = __expf(fmaf(s1[r], scale, -dist[drow[r] + t0 + 16 + m16]));
      laccL[r] += e0 + e1;
      Pw[(quad * 4 + r) * 36 + m16] = e0;
      Pw[(quad * 4 + r) * 36 + 16 + m16] = e1;
    }
    bf16x8v pfr;
    {
      const float* pr = &Pw[m16 * 36 + (quad << 3)];
      float4 pa = *(const float4*)pr;
      float4 pb = *(const float4*)(pr + 4);
      pfr[0] = bf16raw(pa.x); pfr[1] = bf16raw(pa.y);
      pfr[2] = bf16raw(pa.z); pfr[3] = bf16raw(pa.w);
      pfr[4] = bf16raw(pb.x); pfr[5] = bf16raw(pb.y);
      pfr[6] = bf16raw(pb.z); pfr[7] = bf16raw(pb.w);
    }
    bf16x8v vf0 = *(const bf16x8v*)(vts + (size_t)(h * 32 + m16) * 512 + t0 + (quad << 3));
    bf16x8v vf1 = *(const bf16x8v*)(vts + (size_t)(h * 32 + 16 + m16) * 512 + t0 + (quad << 3));
    accO0 = __builtin_amdgcn_mfma_f32_16x16x32_bf16(pfr, vf0, accO0, 0, 0, 0);
    accO1 = __builtin_amdgcn_mfma_f32_16x16x32_bf16(pfr, vf1, accO1, 0, 0, 0);
  }

  float invl[4];
  #pragma unroll
  for (int r = 0; r < 4; ++r) {
    float t = laccL[r];
    t += __shfl_xor(t, 1, 64); t += __shfl_xor(t, 2, 64);
    t += __shfl_xor(t, 4, 64); t += __shfl_xor(t, 8, 64);
    invl[r] = 1.f / t;
  }

  #pragma unroll
  for (int r = 0; r < 4; ++r) {
    size_t orow = (size_t)(b * NN + qbase + quad * 4 + r) * DD + h * 32;
    outg[orow + m16] = __float2bfloat16(accO0[r] * invl[r]);
    outg[orow + 16 + m16] = __float2bfloat16(accO1[r] * invl[r]);
  }

  if (accum) {
    for (int t0 = 0; t0 < NN; t0 += 32) {
      bf16x8v kf0 = *(const bf16x8v*)(qkvs + ((size_t)(b * NN + t0 + m16)) * 768 + 256 + h * 32 + (quad << 3));
      bf16x8v kf1 = *(const bf16x8v*)(qkvs + ((size_t)(b * NN + t0 + 16 + m16)) * 768 + 256 + h * 32 + (quad << 3));
      f32x4v s0 = __builtin_amdgcn_mfma_f32_16x16x32_bf16(qf, kf0, zero, 0, 0, 0);
      f32x4v s1 = __builtin_amdgcn_mfma_f32_16x16x32_bf16(qf, kf1, zero, 0, 0, 0);
      float p0 = 0.f, p1 = 0.f;
      #pragma unroll
      for (int r = 0; r < 4; ++r) {
        p0 += __expf(fmaf(s0[r], scale, -dist[drow[r] + t0 + m16])) * invl[r];
        p1 += __expf(fmaf(s1[r], scale, -dist[drow[r] + t0 + 16 + m16])) * invl[r];
      }
      p0 += __shfl_xor(p0, 16, 64); p0 += __shfl_xor(p0, 32, 64);
      p1 += __shfl_xor(p1, 16, 64); p1 += __shfl_xor(p1, 32, 64);
      if (quad == 0) {
        atomicAdd(&s_acc[b * NN + t0 + m16], p0 * 0.125f);
        atomicAdd(&s_acc[b * NN + t0 + 16 + m16], p1 * 0.125f);
      }
    }
  }
}

// parallel max over dist[b] via float-as-uint atomicMax (values >= 0).
__global__ __launch_bounds__(256) void maxd_kernel(const float* __restrict__ dist,
                                                   unsigned int* __restrict__ maxd) {
  const int b = blockIdx.y;
  const int tid = threadIdx.x;
  const float4* p = (const float4*)(dist + (size_t)b * NN * NN) +
                    blockIdx.x * 8192 + tid;
  float m = 0.f;
  #pragma unroll 8
  for (int i = 0; i < 32; ++i) {
    float4 v = p[i * 256];
    m = fmaxf(m, fmaxf(fmaxf(v.x, v.y), fmaxf(v.z, v.w)));
  }
  #pragma unroll
  for (int o = 32; o > 0; o >>= 1) m = fmaxf(m, __shfl_xor(m, o, 64));
  __shared__ float wm[4];
  if ((tid & 63) == 0) wm[tid >> 6] = m;
  __syncthreads();
  if (tid == 0) {
    float mm = fmaxf(fmaxf(wm[0], wm[1]), fmaxf(wm[2], wm[3]));
    atomicMax(&maxd[b], __float_as_uint(mm));
  }
}

// one block per batch: gather K rows, mean, LN -> out
__global__ __launch_bounds__(256) void pool_ln_kernel(const float* __restrict__ x,
                                                      const int* __restrict__ idx,
                                                      const float* __restrict__ gamma,
                                                      const float* __restrict__ beta,
                                                      float* __restrict__ out) {
  __shared__ float stmp[4];
  __shared__ int sIdx[KSEL];
  const int b = blockIdx.x;
  const int d = threadIdx.x;
  if (d < KSEL) sIdx[d] = idx[b * KSEL + d];
  __syncthreads();
  float acc = 0.f;
  #pragma unroll 4
  for (int kk = 0; kk < KSEL; ++kk)
    acc += x[((size_t)b * NN + sIdx[kk]) * DD + d];
  float p = acc * (1.0f / KSEL);
  float mu = blk_sum_256(p, stmp) * (1.0f / DD);
  float diff = p - mu;
  float var = blk_sum_256(diff * diff, stmp) * (1.0f / DD);
  out[b * DD + d] = diff * rsqrtf(var + 1e-6f) * gamma[d] + beta[d];
}

// ---------------- launcher ----------------
extern "C" void kernel_launch(void* const* d_in, const int* in_sizes, int n_in,
                              void* d_out, int out_size, void* d_ws, size_t ws_size,
                              hipStream_t stream) {
  (void)in_sizes; (void)n_in; (void)out_size; (void)ws_size;
  const float* x_in  = (const float*)d_in[0];
  const float* dist  = (const float*)d_in[1];
  const float* Wq    = (const float*)d_in[3];
  const float* Wk    = (const float*)d_in[4];
  const float* Wv    = (const float*)d_in[5];
  const float* Wo    = (const float*)d_in[6];
  const float* W1    = (const float*)d_in[7];
  const float* W2    = (const float*)d_in[8];
  const float* ln1_g = (const float*)d_in[9];
  const float* ln1_b = (const float*)d_in[10];
  const float* ln2_g = (const float*)d_in[11];
  const float* ln2_b = (const float*)d_in[12];
  const float* gamma = (const float*)d_in[13];
  const float* beta  = (const float*)d_in[14];

  char* wsb = (char*)d_ws;
  float* x              = (float*)(wsb + X_B);
  __hip_bfloat16* qkvb  = (__hip_bfloat16*)(wsb + QKVB_B);
  __hip_bfloat16* vtb   = (__hip_bfloat16*)(wsb + VT_B);
  __hip_bfloat16* ffn   = (__hip_bfloat16*)(wsb + FFN_B);
  __hip_bfloat16* hb    = (__hip_bfloat16*)(wsb + H_B);
  __hip_bfloat16* ab    = (__hip_bfloat16*)(wsb + ATT_B);
  __hip_bfloat16* WqkvT = (__hip_bfloat16*)(wsb + WQKV_B);
  __hip_bfloat16* WoT   = (__hip_bfloat16*)(wsb + WO_B);
  __hip_bfloat16* W1T   = (__hip_bfloat16*)(wsb + W1T_B);
  __hip_bfloat16* W2T   = (__hip_bfloat16*)(wsb + W2T_B);
  float* sbuf = (float*)(wsb + S_B);
  unsigned int* maxdb = (unsigned int*)(wsb + MAXD_B);
  int*   idxb = (int*)(wsb + IDX_B);
  float* dummy = (float*)(wsb + DUMMY_B);
  float* out  = (float*)d_out;

  hipMemsetAsync(sbuf, 0, BB * NN * sizeof(float) + 64, stream);  // sbuf + maxd
  cast_weights_kernel<<<12288, 256, 0, stream>>>(Wq, Wk, Wv, Wo, W1, W2,
                                                 WqkvT, WoT, W1T, W2T);
  maxd_kernel<<<dim3(8, BB), 256, 0, stream>>>(dist, maxdb);

  const int M = BB * NN;  // 8192
  dim3 gqkv(768 / 64, M / 64);   // (12,128)
  dim3 go(DD / 64, M / 64);      // (4,128)
  dim3 goA(DD / 64, M / 64 + 4); // (4,132): y=0..3 are afps+warm blocks
  dim3 gf(DFF / 64, M / 64);     // (16,128)
  dim3 ga(NN / 16, BB);          // (32,16)

  for (int l = 0; l < LL; ++l) {
    const float* xsrc = (l == 0) ? x_in : x;
    ln_cast_kernel<<<M / 4, 256, 0, stream>>>(xsrc, ln1_g + l * DD, ln1_b + l * DD, hb);
    mfma_gemm<3><<<gqkv, 256, 0, stream>>>(hb, WqkvT + (size_t)l * 768 * 256,
                                           qkvb, vtb, M, 768, 256);
    attn_kernel<<<ga, 512, 0, stream>>>(qkvb, vtb, dist, ab, sbuf, (l == LL - 1) ? 1 : 0);
    if (l == LL - 1) {
      wo_gemm_afps<<<goA, 256, 0, stream>>>(ab, WoT + (size_t)l * 65536, xsrc, x,
                                            dist, sbuf, maxdb, idxb, dummy);
    } else {
      mfma_gemm_res<<<go, 256, 0, stream>>>(ab, WoT + (size_t)l * 65536, xsrc, x, DD, 256);
    }
    ln_cast_kernel<<<M / 4, 256, 0, stream>>>(x, ln2_g + l * DD, ln2_b + l * DD, hb);
    mfma_gemm<2><<<gf, 256, 0, stream>>>(hb, W1T + (size_t)l * 262144,
                                         ffn, nullptr, M, DFF, 256);
    mfma_gemm_res<<<go, 256, 0, stream>>>(ffn, W2T + (size_t)l * 262144, x, x, DD, 1024);
  }
  pool_ln_kernel<<<BB, 256, 0, stream>>>(x, idxb, gamma, beta, out);
}

// Round 14
// 632.194 us; speedup vs baseline: 1.0945x; 1.0945x over previous
//
#include <hip/hip_runtime.h>
#include <hip/hip_bf16.h>
#include <math.h>

// Problem: B=16, N=512, D=256, H=8, L=4, DFF=1024, K=128, DH=32
#define BB 16
#define NN 512
#define DD 256
#define HH 8
#define LL 4
#define DFF 1024
#define KSEL 128
#define DH 32

typedef __attribute__((ext_vector_type(8))) short bf16x8v;
typedef __attribute__((ext_vector_type(4))) float f32x4v;

// ---------------- workspace layout (byte offsets) ----------------
static const size_t X_B    = 0;
static const size_t QKVB_B = 8388608;
static const size_t VT_B   = 20971520;
static const size_t FFN_B  = 8388608;    // overlays qkvb+Vt (dead during FFN)
static const size_t H_B    = 25165824;
static const size_t ATT_B  = 29360128;
static const size_t WQKV_B = 33554432;
static const size_t WO_B   = 35127296;
static const size_t W1T_B  = 35651584;
static const size_t W2T_B  = 37748736;
static const size_t S_B    = 39845888;
static const size_t MAXD_B = 39878656;   // S_B + 32768
static const size_t IDX_B  = 39878720;   // MAXD_B + 64
static const size_t DUMMY_B = 39886912;  // IDX_B + 8192

// ---------------- helpers ----------------
__device__ __forceinline__ float gelu_f(float x) {
  float x3 = x * x * x;
  return 0.5f * x * (1.f + tanhf(0.7978845608028654f * (x + 0.044715f * x3)));
}

__device__ __forceinline__ short bf16raw(float v) {
  __hip_bfloat16 h = __float2bfloat16(v);
  return *reinterpret_cast<short*>(&h);
}

__device__ __forceinline__ float blk_sum_256(float v, float* stmp) {
  #pragma unroll
  for (int o = 32; o > 0; o >>= 1) v += __shfl_down(v, o, 64);
  if ((threadIdx.x & 63) == 0) stmp[threadIdx.x >> 6] = v;
  __syncthreads();
  if (threadIdx.x == 0) stmp[0] = stmp[0] + stmp[1] + stmp[2] + stmp[3];
  __syncthreads();
  float r = stmp[0];
  __syncthreads();
  return r;
}

// DPP move of a u64, invalid lanes -> 0 (bound_ctrl=1). CTRL is a DPP code.
template <int CTRL>
__device__ __forceinline__ unsigned long long dpp_mov_u64(unsigned long long x) {
  int lo = __builtin_amdgcn_update_dpp(0, (int)(unsigned)x, CTRL, 0xf, 0xf, true);
  int hi = __builtin_amdgcn_update_dpp(0, (int)(unsigned)(x >> 32), CTRL, 0xf, 0xf, true);
  return ((unsigned long long)(unsigned)hi << 32) | (unsigned)lo;
}

// merge sorted pairs (b1>=b2), (n1>=n2) -> top-2 into (b1,b2)
__device__ __forceinline__ void merge_top2(unsigned long long& b1, unsigned long long& b2,
                                           unsigned long long n1, unsigned long long n2) {
  if (n1 > b1) {
    b2 = (b1 > n2) ? b1 : n2;
    b1 = n1;
  } else {
    b2 = (b2 > n1) ? b2 : n1;
  }
}

// ---------------- kernels ----------------

// one-shot: transpose-cast all weights to bf16.
__global__ __launch_bounds__(256) void cast_weights_kernel(
    const float* __restrict__ Wq, const float* __restrict__ Wk,
    const float* __restrict__ Wv, const float* __restrict__ Wo,
    const float* __restrict__ W1, const float* __restrict__ W2,
    __hip_bfloat16* __restrict__ qkvT, __hip_bfloat16* __restrict__ WoT,
    __hip_bfloat16* __restrict__ W1T, __hip_bfloat16* __restrict__ W2T) {
  int i = blockIdx.x * 256 + threadIdx.x;
  if (i < 786432) {                       // qkvT [L][768 n][256 k]
    int l = i / 196608, r = i % 196608;
    int n = r >> 8, k = r & 255;
    const float* src = (n < 256) ? Wq : (n < 512 ? Wk : Wv);
    qkvT[i] = __float2bfloat16(src[l * 65536 + k * 256 + (n & 255)]);
  } else if (i < 1048576) {               // WoT [L][256][256]
    int j = i - 786432;
    int l = j >> 16, r = j & 65535;
    int n = r >> 8, k = r & 255;
    WoT[j] = __float2bfloat16(Wo[l * 65536 + k * 256 + n]);
  } else if (i < 2097152) {               // W1T [L][1024 n][256 k]
    int j = i - 1048576;
    int l = j >> 18, r = j & 262143;
    int n = r >> 8, k = r & 255;
    W1T[j] = __float2bfloat16(W1[l * 262144 + k * 1024 + n]);
  } else {                                // W2T [L][256 n][1024 k]
    int j = i - 2097152;
    int l = j >> 18, r = j & 262143;
    int n = r >> 10, k = r & 1023;
    W2T[j] = __float2bfloat16(W2[l * 262144 + k * 256 + n]);
  }
}

// LayerNorm, writes bf16. One wave per row, shfl reductions, no LDS.
__global__ __launch_bounds__(256) void ln_cast_kernel(const float* __restrict__ in,
                                                      const float* __restrict__ g,
                                                      const float* __restrict__ bb,
                                                      __hip_bfloat16* __restrict__ out) {
  const int tid = threadIdx.x;
  const int lane = tid & 63;
  const size_t row = (size_t)blockIdx.x * 4 + (tid >> 6);
  const float4 v = *(const float4*)(in + row * DD + lane * 4);
  float s1 = v.x + v.y + v.z + v.w;
  #pragma unroll
  for (int o = 32; o > 0; o >>= 1) s1 += __shfl_xor(s1, o, 64);
  const float mu = s1 * (1.f / DD);
  const float d0 = v.x - mu, d1 = v.y - mu, d2 = v.z - mu, d3 = v.w - mu;
  float s2 = d0 * d0 + d1 * d1 + d2 * d2 + d3 * d3;
  #pragma unroll
  for (int o = 32; o > 0; o >>= 1) s2 += __shfl_xor(s2, o, 64);
  const float rsig = rsqrtf(s2 * (1.f / DD) + 1e-6f);
  const float4 gg = *(const float4*)(g + lane * 4);
  const float4 bv = *(const float4*)(bb + lane * 4);
  short4 o;
  o.x = bf16raw(d0 * rsig * gg.x + bv.x);
  o.y = bf16raw(d1 * rsig * gg.y + bv.y);
  o.z = bf16raw(d2 * rsig * gg.z + bv.z);
  o.w = bf16raw(d3 * rsig * gg.w + bv.w);
  *(short4*)((short*)out + row * DD + lane * 4) = o;
}

// MFMA bf16 GEMM (64x64 tile, BK=32, 4 waves) — proven R12 configuration.
// MODE 2: bf16 out = gelu(acc);
// MODE 3: qkv: cols<512 -> bf16 qkvb (pitch 768); cols>=512 -> Vt[b][dim][key].
template <int MODE>
__global__ __launch_bounds__(256) void mfma_gemm(const __hip_bfloat16* __restrict__ A,
                                                 const __hip_bfloat16* __restrict__ Bt,
                                                 void* __restrict__ Cv,
                                                 __hip_bfloat16* __restrict__ Vto,
                                                 int M, int N, int Kd) {
  __shared__ short As[64 * 40];
  __shared__ short Bs[64 * 40];
  const int tid = threadIdx.x;
  const int w = tid >> 6, lane = tid & 63;
  const int m16 = lane & 15, quad = lane >> 4;
  const int bm = blockIdx.y << 6, bn = blockIdx.x << 6;
  const int srow = tid >> 2, scol = (tid & 3) << 3;

  f32x4v acc[4];
  #pragma unroll
  for (int nt = 0; nt < 4; ++nt) acc[nt] = (f32x4v){0.f, 0.f, 0.f, 0.f};

  const short* Ag = (const short*)A;
  const short* Bg = (const short*)Bt;

  for (int k0 = 0; k0 < Kd; k0 += 32) {
    *(bf16x8v*)&As[srow * 40 + scol] =
        *(const bf16x8v*)(Ag + (size_t)(bm + srow) * Kd + k0 + scol);
    *(bf16x8v*)&Bs[srow * 40 + scol] =
        *(const bf16x8v*)(Bg + (size_t)(bn + srow) * Kd + k0 + scol);
    __syncthreads();
    bf16x8v af = *(bf16x8v*)&As[(w * 16 + m16) * 40 + (quad << 3)];
    #pragma unroll
    for (int nt = 0; nt < 4; ++nt) {
      bf16x8v bf = *(bf16x8v*)&Bs[(nt * 16 + m16) * 40 + (quad << 3)];
      acc[nt] = __builtin_amdgcn_mfma_f32_16x16x32_bf16(af, bf, acc[nt], 0, 0, 0);
    }
    __syncthreads();
  }

  const int erow = bm + w * 16 + quad * 4;
  #pragma unroll
  for (int nt = 0; nt < 4; ++nt) {
    int col = bn + nt * 16 + m16;
    if (MODE == 3) {
      if (col < 512) {
        #pragma unroll
        for (int r = 0; r < 4; ++r)
          ((__hip_bfloat16*)Cv)[(size_t)(erow + r) * 768 + col] =
              __float2bfloat16(acc[nt][r]);
      } else {
        short4 pk;
        pk.x = bf16raw(acc[nt][0]); pk.y = bf16raw(acc[nt][1]);
        pk.z = bf16raw(acc[nt][2]); pk.w = bf16raw(acc[nt][3]);
        int bb2 = erow >> 9, key = erow & 511, dim = col - 512;
        *(short4*)((short*)Vto + (size_t)bb2 * 131072 + (size_t)dim * 512 + key) = pk;
      }
    } else {
      #pragma unroll
      for (int r = 0; r < 4; ++r)
        ((__hip_bfloat16*)Cv)[(size_t)(erow + r) * N + col] =
            __float2bfloat16(gelu_f(acc[nt][r]));
    }
  }
}

// gemm body (BK=32): fp32 out = acc + Res (Wo / FFN2). bm passed in.
__device__ __forceinline__ void gemm_res_body(const __hip_bfloat16* __restrict__ A,
                                              const __hip_bfloat16* __restrict__ Bt,
                                              const float* __restrict__ Res,
                                              float* __restrict__ C,
                                              int N, int Kd, int bm,
                                              short* As, short* Bs) {
  const int tid = threadIdx.x;
  const int w = tid >> 6, lane = tid & 63;
  const int m16 = lane & 15, quad = lane >> 4;
  const int bn = blockIdx.x << 6;
  const int srow = tid >> 2, scol = (tid & 3) << 3;

  f32x4v acc[4];
  #pragma unroll
  for (int nt = 0; nt < 4; ++nt) acc[nt] = (f32x4v){0.f, 0.f, 0.f, 0.f};

  const short* Ag = (const short*)A;
  const short* Bg = (const short*)Bt;

  for (int k0 = 0; k0 < Kd; k0 += 32) {
    *(bf16x8v*)&As[srow * 40 + scol] =
        *(const bf16x8v*)(Ag + (size_t)(bm + srow) * Kd + k0 + scol);
    *(bf16x8v*)&Bs[srow * 40 + scol] =
        *(const bf16x8v*)(Bg + (size_t)(bn + srow) * Kd + k0 + scol);
    __syncthreads();
    bf16x8v af = *(bf16x8v*)&As[(w * 16 + m16) * 40 + (quad << 3)];
    #pragma unroll
    for (int nt = 0; nt < 4; ++nt) {
      bf16x8v bf = *(bf16x8v*)&Bs[(nt * 16 + m16) * 40 + (quad << 3)];
      acc[nt] = __builtin_amdgcn_mfma_f32_16x16x32_bf16(af, bf, acc[nt], 0, 0, 0);
    }
    __syncthreads();
  }

  const int erow = bm + w * 16 + quad * 4;
  #pragma unroll
  for (int nt = 0; nt < 4; ++nt) {
    int col = bn + nt * 16 + m16;
    #pragma unroll
    for (int r = 0; r < 4; ++r) {
      size_t off = (size_t)(erow + r) * N + col;
      C[off] = acc[nt][r] + Res[off];
    }
  }
}

__global__ __launch_bounds__(256) void mfma_gemm_res(const __hip_bfloat16* __restrict__ A,
                                                     const __hip_bfloat16* __restrict__ Bt,
                                                     const float* __restrict__ Res,
                                                     float* __restrict__ C,
                                                     int N, int Kd) {
  __shared__ short As[64 * 40];
  __shared__ short Bs[64 * 40];
  gemm_res_body(A, Bt, Res, C, N, Kd, blockIdx.y << 6, As, Bs);
}

// AFPS selection for ONE batch, one wave. DPP top-2 argmax + 1-deep spec.
__device__ void afps_wave(int b, int lane,
                          const float* __restrict__ dist,
                          const float* __restrict__ s,
                          const unsigned int* __restrict__ maxd,
                          int* __restrict__ idx_out) {
  const float* db = dist + (size_t)b * NN * NN;

  float sv[8];
  float ms = 0.f;
  #pragma unroll
  for (int r = 0; r < 8; ++r) {
    sv[r] = s[b * NN + r * 64 + lane];
    ms = fmaxf(ms, sv[r]);
  }
  #pragma unroll
  for (int o = 32; o > 0; o >>= 1) ms = fmaxf(ms, __shfl_xor(ms, o, 64));

  const float invmaxd = 1.0f / __uint_as_float(maxd[b]);
  float sn[8], mind[8];
  #pragma unroll
  for (int r = 0; r < 8; ++r) {
    sn[r] = (sv[r] / ms) * 0.1f;
    mind[r] = db[r * 64 + lane] * invmaxd + sn[r];   // row 0 == col 0 (sym)
  }
  unsigned selm = (lane == 0) ? 1u : 0u;
  if (lane == 0) idx_out[b * KSEL + 0] = 0;

  int specIdx = -1;
  float sreg[8];

  for (int it = 1; it < KSEL; ++it) {
    unsigned long long b1 = 0ull, b2 = 0ull;
    #pragma unroll
    for (int r = 0; r < 8; ++r) {
      unsigned long long pk =
          ((selm >> r) & 1u) ? 0ull
            : (((unsigned long long)__float_as_uint(mind[r])) << 32) |
              (unsigned)(511 - (r * 64 + lane));
      if (pk > b1) { b2 = b1; b1 = pk; }
      else if (pk > b2) b2 = pk;
    }
    { unsigned long long n1 = dpp_mov_u64<0x111>(b1), n2 = dpp_mov_u64<0x111>(b2); merge_top2(b1, b2, n1, n2); }
    { unsigned long long n1 = dpp_mov_u64<0x112>(b1), n2 = dpp_mov_u64<0x112>(b2); merge_top2(b1, b2, n1, n2); }
    { unsigned long long n1 = dpp_mov_u64<0x114>(b1), n2 = dpp_mov_u64<0x114>(b2); merge_top2(b1, b2, n1, n2); }
    { unsigned long long n1 = dpp_mov_u64<0x118>(b1), n2 = dpp_mov_u64<0x118>(b2); merge_top2(b1, b2, n1, n2); }
    { unsigned long long n1 = dpp_mov_u64<0x142>(b1), n2 = dpp_mov_u64<0x142>(b2); merge_top2(b1, b2, n1, n2); }
    { unsigned long long n1 = dpp_mov_u64<0x143>(b1), n2 = dpp_mov_u64<0x143>(b2); merge_top2(b1, b2, n1, n2); }
    const unsigned w1 = (unsigned)__builtin_amdgcn_readlane((int)(unsigned)b1, 63);
    const unsigned w2 = (unsigned)__builtin_amdgcn_readlane((int)(unsigned)b2, 63);
    const int nw = 511 - (int)(w1 & 0x1ffu);
    const int sec = 511 - (int)(w2 & 0x1ffu);

    float rowv[8];
    if (nw == specIdx) {
      #pragma unroll
      for (int r = 0; r < 8; ++r) rowv[r] = sreg[r];
    } else {
      const float* row = db + (size_t)nw * NN;
      #pragma unroll
      for (int r = 0; r < 8; ++r) rowv[r] = row[r * 64 + lane];
    }
    {
      const float* srow = db + (size_t)sec * NN;
      #pragma unroll
      for (int r = 0; r < 8; ++r) sreg[r] = srow[r * 64 + lane];
      specIdx = sec;
    }
    if (lane == (nw & 63)) selm |= 1u << (nw >> 6);
    if (lane == 0) idx_out[b * KSEL + it] = nw;
    #pragma unroll
    for (int r = 0; r < 8; ++r)
      mind[r] = fminf(mind[r], fmaf(rowv[r], invmaxd, sn[r]));
  }
}

// Layer-3 Wo GEMM with AFPS fused in grid-y slices 0..3 (dispatched first):
// 16 blocks, one per batch: wave 0 = selector; waves 1-3 warm dist[b] into
// this CU's XCD L2. gemm blocks use y-4 as row tile.
__global__ __launch_bounds__(256) void wo_gemm_afps(const __hip_bfloat16* __restrict__ A,
                                                    const __hip_bfloat16* __restrict__ Bt,
                                                    const float* __restrict__ Res,
                                                    float* __restrict__ C,
                                                    const float* __restrict__ dist,
                                                    const float* __restrict__ s,
                                                    const unsigned int* __restrict__ maxd,
                                                    int* __restrict__ idx_out,
                                                    float* __restrict__ dummy) {
  __shared__ short As[64 * 40];
  __shared__ short Bs[64 * 40];
  if (blockIdx.y < 4) {
    const int b = blockIdx.y * 4 + blockIdx.x;   // grid.x == 4
    const int wv = threadIdx.x >> 6, lane = threadIdx.x & 63;
    if (wv == 0) {
      afps_wave(b, lane, dist, s, maxd, idx_out);
    } else {
      const float4* p = (const float4*)(dist + (size_t)b * NN * NN);
      float acc = 0.f;
      for (int i = (wv - 1) * 64 + lane; i < 65536; i += 192) acc += p[i].x;
      if (acc == 123.456789f) atomicAdd(dummy, 1.f);  // never true; keeps loads
    }
    return;
  }
  gemm_res_body(A, Bt, Res, C, DD, 256, (blockIdx.y - 4) << 6, As, Bs);
}

// MFMA flash attention, barrier-free main loop; accum pass reduces s into
// LDS per block, then one global atomic per key per block (8x fewer atomics).
__global__ __launch_bounds__(512) void attn_kernel(const __hip_bfloat16* __restrict__ qkvb,
                                                   const __hip_bfloat16* __restrict__ vt,
                                                   const float* __restrict__ dist,
                                                   __hip_bfloat16* __restrict__ outg,
                                                   float* __restrict__ s_acc,
                                                   int accum) {
  __shared__ float Pf[8][16 * 36];
  const int tid = threadIdx.x;
  const int h = tid >> 6, lane = tid & 63;
  const int m16 = lane & 15, quad = lane >> 4;
  const int b = blockIdx.y;
  const int qbase = blockIdx.x * 16;
  const float scale = 0.17677669529663687f;
  const f32x4v zero = {0.f, 0.f, 0.f, 0.f};

  const short* qkvs = (const short*)qkvb;
  const short* vts = (const short*)vt + (size_t)b * 131072;
  float* Pw = Pf[h];

  bf16x8v qf = *(const bf16x8v*)(qkvs + ((size_t)(b * NN + qbase + m16)) * 768 + h * 32 + (quad << 3));

  int drow[4];
  #pragma unroll
  for (int r = 0; r < 4; ++r) drow[r] = (b * NN + qbase + quad * 4 + r) * NN;

  f32x4v accO0 = zero, accO1 = zero;
  float laccL[4] = {0.f, 0.f, 0.f, 0.f};

  for (int t0 = 0; t0 < NN; t0 += 32) {
    bf16x8v kf0 = *(const bf16x8v*)(qkvs + ((size_t)(b * NN + t0 + m16)) * 768 + 256 + h * 32 + (quad << 3));
    bf16x8v kf1 = *(const bf16x8v*)(qkvs + ((size_t)(b * NN + t0 + 16 + m16)) * 768 + 256 + h * 32 + (quad << 3));
    f32x4v s0 = __builtin_amdgcn_mfma_f32_16x16x32_bf16(qf, kf0, zero, 0, 0, 0);
    f32x4v s1 = __builtin_amdgcn_mfma_f32_16x16x32_bf16(qf, kf1, zero, 0, 0, 0);
    #pragma unroll
    for (int r = 0; r < 4; ++r) {
      float e0 = __expf(fmaf(s0[r], scale, -dist[drow[r] + t0 + m16]));
      float e1 = __expf(fmaf(s1[r], scale, -dist[drow[r] + t0 + 16 + m16]));
      laccL[r] += e0 + e1;
      Pw[(quad * 4 + r) * 36 + m16] = e0;
      Pw[(quad * 4 + r) * 36 + 16 + m16] = e1;
    }
    bf16x8v pfr;
    {
      const float* pr = &Pw[m16 * 36 + (quad << 3)];
      float4 pa = *(const float4*)pr;
      float4 pb = *(const float4*)(pr + 4);
      pfr[0] = bf16raw(pa.x); pfr[1] = bf16raw(pa.y);
      pfr[2] = bf16raw(pa.z); pfr[3] = bf16raw(pa.w);
      pfr[4] = bf16raw(pb.x); pfr[5] = bf16raw(pb.y);
      pfr[6] = bf16raw(pb.z); pfr[7] = bf16raw(pb.w);
    }
    bf16x8v vf0 = *(const bf16x8v*)(vts + (size_t)(h * 32 + m16) * 512 + t0 + (quad << 3));
    bf16x8v vf1 = *(const bf16x8v*)(vts + (size_t)(h * 32 + 16 + m16) * 512 + t0 + (quad << 3));
    accO0 = __builtin_amdgcn_mfma_f32_16x16x32_bf16(pfr, vf0, accO0, 0, 0, 0);
    accO1 = __builtin_amdgcn_mfma_f32_16x16x32_bf16(pfr, vf1, accO1, 0, 0, 0);
  }

  float invl[4];
  #pragma unroll
  for (int r = 0; r < 4; ++r) {
    float t = laccL[r];
    t += __shfl_xor(t, 1, 64); t += __shfl_xor(t, 2, 64);
    t += __shfl_xor(t, 4, 64); t += __shfl_xor(t, 8, 64);
    invl[r] = 1.f / t;
  }

  #pragma unroll
  for (int r = 0; r < 4; ++r) {
    size_t orow = (size_t)(b * NN + qbase + quad * 4 + r) * DD + h * 32;
    outg[orow + m16] = __float2bfloat16(accO0[r] * invl[r]);
    outg[orow + 16 + m16] = __float2bfloat16(accO1[r] * invl[r]);
  }

  if (accum) {
    // block-level s accumulator in LDS (reuse Pf storage after barrier)
    float* sAcc = &Pf[0][0];
    __syncthreads();
    sAcc[tid] = 0.f;
    __syncthreads();
    for (int t0 = 0; t0 < NN; t0 += 32) {
      bf16x8v kf0 = *(const bf16x8v*)(qkvs + ((size_t)(b * NN + t0 + m16)) * 768 + 256 + h * 32 + (quad << 3));
      bf16x8v kf1 = *(const bf16x8v*)(qkvs + ((size_t)(b * NN + t0 + 16 + m16)) * 768 + 256 + h * 32 + (quad << 3));
      f32x4v s0 = __builtin_amdgcn_mfma_f32_16x16x32_bf16(qf, kf0, zero, 0, 0, 0);
      f32x4v s1 = __builtin_amdgcn_mfma_f32_16x16x32_bf16(qf, kf1, zero, 0, 0, 0);
      float p0 = 0.f, p1 = 0.f;
      #pragma unroll
      for (int r = 0; r < 4; ++r) {
        p0 += __expf(fmaf(s0[r], scale, -dist[drow[r] + t0 + m16])) * invl[r];
        p1 += __expf(fmaf(s1[r], scale, -dist[drow[r] + t0 + 16 + m16])) * invl[r];
      }
      p0 += __shfl_xor(p0, 16, 64); p0 += __shfl_xor(p0, 32, 64);
      p1 += __shfl_xor(p1, 16, 64); p1 += __shfl_xor(p1, 32, 64);
      if (quad == 0) {
        atomicAdd(&sAcc[t0 + m16], p0);
        atomicAdd(&sAcc[t0 + 16 + m16], p1);
      }
    }
    __syncthreads();
    atomicAdd(&s_acc[b * NN + tid], sAcc[tid] * 0.125f);
  }
}

// parallel max over dist[b] via float-as-uint atomicMax (values >= 0).
__global__ __launch_bounds__(256) void maxd_kernel(const float* __restrict__ dist,
                                                   unsigned int* __restrict__ maxd) {
  const int b = blockIdx.y;
  const int tid = threadIdx.x;
  const float4* p = (const float4*)(dist + (size_t)b * NN * NN) +
                    blockIdx.x * 8192 + tid;
  float m = 0.f;
  #pragma unroll 8
  for (int i = 0; i < 32; ++i) {
    float4 v = p[i * 256];
    m = fmaxf(m, fmaxf(fmaxf(v.x, v.y), fmaxf(v.z, v.w)));
  }
  #pragma unroll
  for (int o = 32; o > 0; o >>= 1) m = fmaxf(m, __shfl_xor(m, o, 64));
  __shared__ float wm[4];
  if ((tid & 63) == 0) wm[tid >> 6] = m;
  __syncthreads();
  if (tid == 0) {
    float mm = fmaxf(fmaxf(wm[0], wm[1]), fmaxf(wm[2], wm[3]));
    atomicMax(&maxd[b], __float_as_uint(mm));
  }
}

// one block per batch: gather K rows, mean, LN -> out
__global__ __launch_bounds__(256) void pool_ln_kernel(const float* __restrict__ x,
                                                      const int* __restrict__ idx,
                                                      const float* __restrict__ gamma,
                                                      const float* __restrict__ beta,
                                                      float* __restrict__ out) {
  __shared__ float stmp[4];
  __shared__ int sIdx[KSEL];
  const int b = blockIdx.x;
  const int d = threadIdx.x;
  if (d < KSEL) sIdx[d] = idx[b * KSEL + d];
  __syncthreads();
  float acc = 0.f;
  #pragma unroll 4
  for (int kk = 0; kk < KSEL; ++kk)
    acc += x[((size_t)b * NN + sIdx[kk]) * DD + d];
  float p = acc * (1.0f / KSEL);
  float mu = blk_sum_256(p, stmp) * (1.0f / DD);
  float diff = p - mu;
  float var = blk_sum_256(diff * diff, stmp) * (1.0f / DD);
  out[b * DD + d] = diff * rsqrtf(var + 1e-6f) * gamma[d] + beta[d];
}

// ---------------- launcher ----------------
extern "C" void kernel_launch(void* const* d_in, const int* in_sizes, int n_in,
                              void* d_out, int out_size, void* d_ws, size_t ws_size,
                              hipStream_t stream) {
  (void)in_sizes; (void)n_in; (void)out_size; (void)ws_size;
  const float* x_in  = (const float*)d_in[0];
  const float* dist  = (const float*)d_in[1];
  const float* Wq    = (const float*)d_in[3];
  const float* Wk    = (const float*)d_in[4];
  const float* Wv    = (const float*)d_in[5];
  const float* Wo    = (const float*)d_in[6];
  const float* W1    = (const float*)d_in[7];
  const float* W2    = (const float*)d_in[8];
  const float* ln1_g = (const float*)d_in[9];
  const float* ln1_b = (const float*)d_in[10];
  const float* ln2_g = (const float*)d_in[11];
  const float* ln2_b = (const float*)d_in[12];
  const float* gamma = (const float*)d_in[13];
  const float* beta  = (const float*)d_in[14];

  char* wsb = (char*)d_ws;
  float* x              = (float*)(wsb + X_B);
  __hip_bfloat16* qkvb  = (__hip_bfloat16*)(wsb + QKVB_B);
  __hip_bfloat16* vtb   = (__hip_bfloat16*)(wsb + VT_B);
  __hip_bfloat16* ffn   = (__hip_bfloat16*)(wsb + FFN_B);
  __hip_bfloat16* hb    = (__hip_bfloat16*)(wsb + H_B);
  __hip_bfloat16* ab    = (__hip_bfloat16*)(wsb + ATT_B);
  __hip_bfloat16* WqkvT = (__hip_bfloat16*)(wsb + WQKV_B);
  __hip_bfloat16* WoT   = (__hip_bfloat16*)(wsb + WO_B);
  __hip_bfloat16* W1T   = (__hip_bfloat16*)(wsb + W1T_B);
  __hip_bfloat16* W2T   = (__hip_bfloat16*)(wsb + W2T_B);
  float* sbuf = (float*)(wsb + S_B);
  unsigned int* maxdb = (unsigned int*)(wsb + MAXD_B);
  int*   idxb = (int*)(wsb + IDX_B);
  float* dummy = (float*)(wsb + DUMMY_B);
  float* out  = (float*)d_out;

  hipMemsetAsync(sbuf, 0, BB * NN * sizeof(float) + 64, stream);  // sbuf + maxd
  cast_weights_kernel<<<12288, 256, 0, stream>>>(Wq, Wk, Wv, Wo, W1, W2,
                                                 WqkvT, WoT, W1T, W2T);
  maxd_kernel<<<dim3(8, BB), 256, 0, stream>>>(dist, maxdb);

  const int M = BB * NN;  // 8192
  dim3 gqkv(768 / 64, M / 64);   // (12,128)
  dim3 go(DD / 64, M / 64);      // (4,128)
  dim3 goA(DD / 64, M / 64 + 4); // (4,132): y=0..3 are afps+warm blocks
  dim3 gf(DFF / 64, M / 64);     // (16,128)
  dim3 ga(NN / 16, BB);          // (32,16)

  for (int l = 0; l < LL; ++l) {
    const float* xsrc = (l == 0) ? x_in : x;
    ln_cast_kernel<<<M / 4, 256, 0, stream>>>(xsrc, ln1_g + l * DD, ln1_b + l * DD, hb);
    mfma_gemm<3><<<gqkv, 256, 0, stream>>>(hb, WqkvT + (size_t)l * 768 * 256,
                                           qkvb, vtb, M, 768, 256);
    attn_kernel<<<ga, 512, 0, stream>>>(qkvb, vtb, dist, ab, sbuf, (l == LL - 1) ? 1 : 0);
    if (l == LL - 1) {
      wo_gemm_afps<<<goA, 256, 0, stream>>>(ab, WoT + (size_t)l * 65536, xsrc, x,
                                            dist, sbuf, maxdb, idxb, dummy);
    } else {
      mfma_gemm_res<<<go, 256, 0, stream>>>(ab, WoT + (size_t)l * 65536, xsrc, x, DD, 256);
    }
    ln_cast_kernel<<<M / 4, 256, 0, stream>>>(x, ln2_g + l * DD, ln2_b + l * DD, hb);
    mfma_gemm<2><<<gf, 256, 0, stream>>>(hb, W1T + (size_t)l * 262144,
                                         ffn, nullptr, M, DFF, 256);
    mfma_gemm_res<<<go, 256, 0, stream>>>(ffn, W2T + (size_t)l * 262144, x, x, DD, 1024);
  }
  pool_ln_kernel<<<BB, 256, 0, stream>>>(x, idxb, gamma, beta, out);
}